// Round 1
// baseline (416.369 us; speedup 1.0000x reference)
//
#include <hip/hip_runtime.h>

typedef __bf16 bf16;
typedef __attribute__((ext_vector_type(8))) __bf16 bf16x8;
typedef __attribute__((ext_vector_type(4))) float f32x4;

#define NBATCH 8
#define NHEAD  12
#define SEQ    2048
#define DH     64
#define CDIM   768
#define MROWS  (NBATCH*SEQ)   /* 16384 */
#define NQKV   (3*CDIM)       /* 2304  */

__device__ __forceinline__ f32x4 mfma16(bf16x8 a, bf16x8 b, f32x4 c) {
  return __builtin_amdgcn_mfma_f32_16x16x32_bf16(a, b, c, 0, 0, 0);
}

// async global->LDS, 16B per lane; LDS dest must be the wave-uniform base
// (HW writes base + lane*16) -- guide m104/m97.
__device__ __forceinline__ void gload_lds16(const void* g, void* l) {
  __builtin_amdgcn_global_load_lds((const __attribute__((address_space(1))) void*)g,
                                   (__attribute__((address_space(3))) void*)l,
                                   16, 0, 0);
}

// ---------------- fp32 -> bf16 convert (vectorized, G13) ----------------
__global__ void cvt_bf16(const float* __restrict__ src, bf16* __restrict__ dst, int n8) {
  int i = blockIdx.x * 256 + threadIdx.x;
  if (i >= n8) return;
  const float4* s4 = (const float4*)src;
  float4 a = s4[2*i], c = s4[2*i+1];
  bf16x8 o;
  o[0]=(bf16)a.x; o[1]=(bf16)a.y; o[2]=(bf16)a.z; o[3]=(bf16)a.w;
  o[4]=(bf16)c.x; o[5]=(bf16)c.y; o[6]=(bf16)c.z; o[7]=(bf16)c.w;
  *(bf16x8*)(dst + (size_t)i*8) = o;
}

// ---------------- GEMM: C[M,N] = A[M,K] * B[N,K]^T  (both K-major) -------
// 128x128 tile, BK=32, 4 waves (2x2), 4x4 16x16x32 bf16 MFMA frags/wave.
// LDS XOR swizzle (slot ^ row&3 on 64B rows) applied both-sides:
// pre-swizzled GLOBAL source + linear global_load_lds dest + swizzled ds_read.
template <int OUT_F32>
__global__ __launch_bounds__(256, 2)
void gemm_bt(const bf16* __restrict__ A, const bf16* __restrict__ Bm,
             void* __restrict__ Cout, const float* __restrict__ bias,
             int M, int Nn, int K) {
  __shared__ bf16 As[128*32];
  __shared__ bf16 Bs[128*32];
  const int tid = threadIdx.x, wid = tid >> 6, lane = tid & 63;
  const int g = lane >> 4, ln = lane & 15;
  const int ntm = M >> 7, ntn = Nn >> 7;
  // tile-group swizzle: 32 tm-tiles per group share the whole B panel in L2
  const int gsz = 32 * ntn;
  const int grp = blockIdx.x / gsz;
  const int rem = blockIdx.x - grp * gsz;
  const int tm = grp * 32 + (rem & 31);
  const int tn = rem >> 5;
  (void)ntm;
  const int m0 = tm << 7, n0 = tn << 7;
  const int wr = wid >> 1, wc = wid & 1;

  const int srow = lane >> 2;   // row-within-chunk (16 rows x 64B per 1KB chunk)
  const int sslot = lane & 3;   // 16B slot within 64B row

  f32x4 acc[4][4] = {};

  const int nkt = K >> 5;
  for (int kt = 0; kt < nkt; ++kt) {
    if (kt) __syncthreads();
    #pragma unroll
    for (int i = 0; i < 2; ++i) {
      int c = wid * 2 + i;           // chunks 0..7
      int row = c * 16 + srow;
      int colA = kt * 32 + ((sslot ^ (row & 3)) << 3);  // pre-swizzled source
      gload_lds16(A + (size_t)(m0 + row) * K + colA, &As[c * 512]);
      gload_lds16(Bm + (size_t)(n0 + row) * K + colA, &Bs[c * 512]);
    }
    __syncthreads();

    bf16x8 aF[4], bF[4];
    #pragma unroll
    for (int m = 0; m < 4; ++m) {
      int row = wr * 64 + m * 16 + ln;
      aF[m] = *(const bf16x8*)&As[row * 32 + ((g ^ (row & 3)) << 3)];
    }
    #pragma unroll
    for (int n = 0; n < 4; ++n) {
      int row = wc * 64 + n * 16 + ln;
      bF[n] = *(const bf16x8*)&Bs[row * 32 + ((g ^ (row & 3)) << 3)];
    }
    #pragma unroll
    for (int m = 0; m < 4; ++m)
      #pragma unroll
      for (int n = 0; n < 4; ++n)
        acc[m][n] = mfma16(aF[m], bF[n], acc[m][n]);
  }

  // epilogue; C/D layout: col = lane&15, row = (lane>>4)*4 + reg  (m89)
  #pragma unroll
  for (int m = 0; m < 4; ++m) {
    int rowb = m0 + wr * 64 + m * 16 + g * 4;
    #pragma unroll
    for (int n = 0; n < 4; ++n) {
      int col = n0 + wc * 64 + n * 16 + ln;
      float bv = OUT_F32 ? bias[col] : 0.f;
      #pragma unroll
      for (int r = 0; r < 4; ++r) {
        if (OUT_F32)
          ((float*)Cout)[(size_t)(rowb + r) * Nn + col] = acc[m][n][r] + bv;
        else
          ((bf16*)Cout)[(size_t)(rowb + r) * Nn + col] = (bf16)acc[m][n][r];
      }
    }
  }
}

// ---------------- split qkv -> Q, K ([B,H,N,D]) and Vt ([B,H,D,N]) -------
__global__ __launch_bounds__(256)
void split_qkv(const bf16* __restrict__ qkv, bf16* __restrict__ Q,
               bf16* __restrict__ K, bf16* __restrict__ Vt) {
  __shared__ bf16 vlds[64 * 72];   // padded: 144B rows -> 2-way banks (free)
  const int nt = blockIdx.x, bh = blockIdx.y;
  const int b = bh / NHEAD, h = bh % NHEAD;
  const int tid = threadIdx.x;
  const int nl = tid >> 2, quad = tid & 3;

  const size_t srow = (size_t)(b * SEQ + nt * 64 + nl) * NQKV;
  const size_t drow = ((size_t)bh * SEQ + nt * 64 + nl) * DH;
  // Q
  {
    const bf16* s = qkv + srow + h * 64 + quad * 16;
    bf16* d = Q + drow + quad * 16;
    *(bf16x8*)d = *(const bf16x8*)s;
    *(bf16x8*)(d + 8) = *(const bf16x8*)(s + 8);
  }
  // K
  {
    const bf16* s = qkv + srow + CDIM + h * 64 + quad * 16;
    bf16* d = K + drow + quad * 16;
    *(bf16x8*)d = *(const bf16x8*)s;
    *(bf16x8*)(d + 8) = *(const bf16x8*)(s + 8);
  }
  // V -> LDS
  {
    const bf16* s = qkv + srow + 2 * CDIM + h * 64 + quad * 16;
    *(bf16x8*)&vlds[nl * 72 + quad * 16] = *(const bf16x8*)s;
    *(bf16x8*)&vlds[nl * 72 + quad * 16 + 8] = *(const bf16x8*)(s + 8);
  }
  __syncthreads();
  // LDS -> Vt (transposed, coalesced 16B writes)
  {
    const int dl = tid >> 2;
    bf16x8 w0, w1;
    #pragma unroll
    for (int j = 0; j < 8; ++j) {
      w0[j] = vlds[(quad * 16 + j) * 72 + dl];
      w1[j] = vlds[(quad * 16 + 8 + j) * 72 + dl];
    }
    bf16* d = Vt + ((size_t)bh * DH + dl) * SEQ + nt * 64 + quad * 16;
    *(bf16x8*)d = w0;
    *(bf16x8*)(d + 8) = w1;
  }
}

// ---------------- flash attention fwd ------------------------------------
// grid (32 qtiles, 96 bh), 256 thr. Q-tile 64 (16 rows/wave), KV-tile 64.
// K/Vt staged with row&7 XOR swizzle (2-way banks = free). Online softmax in
// log2 domain, wave-parallel over the 16-lane group. P relayout via 144B-
// stride padded LDS.
__global__ __launch_bounds__(256, 2)
void attn_fwd(const bf16* __restrict__ Q, const bf16* __restrict__ K,
              const bf16* __restrict__ Vt, bf16* __restrict__ Oa) {
  __shared__ bf16 Ks[64 * 64];
  __shared__ bf16 Vs[64 * 64];
  __shared__ bf16 Ps[4][16 * 72];
  const int tid = threadIdx.x, wid = tid >> 6, lane = tid & 63;
  const int g = lane >> 4, ln = lane & 15;
  const int qt = blockIdx.x, bh = blockIdx.y;
  const bf16* Qp = Q + (size_t)bh * SEQ * DH;
  const bf16* Kp = K + (size_t)bh * SEQ * DH;
  const bf16* Vp = Vt + (size_t)bh * DH * SEQ;

  const int q0 = qt * 64 + wid * 16;
  bf16x8 qF[2];
  #pragma unroll
  for (int kk = 0; kk < 2; ++kk)
    qF[kk] = *(const bf16x8*)(Qp + (size_t)(q0 + ln) * DH + kk * 32 + g * 8);

  f32x4 o[4] = {};
  float mrun[4], lrun[4];
  #pragma unroll
  for (int r = 0; r < 4; ++r) { mrun[r] = -3.0e38f; lrun[r] = 0.f; }

  const float SC = 0.125f * 1.44269504088896f;  // D^-0.5 * log2(e)
  const int srowk = lane >> 3, sslot = lane & 7;

  for (int t = 0; t < SEQ / 64; ++t) {
    if (t) __syncthreads();
    #pragma unroll
    for (int i = 0; i < 2; ++i) {
      int c = wid * 2 + i;                 // chunks 0..7 (8 rows x 128B each)
      int row = c * 8 + srowk;
      int scol = ((sslot ^ (row & 7)) << 3);  // pre-swizzled source (elems)
      gload_lds16(Kp + (size_t)(t * 64 + row) * DH + scol, &Ks[c * 512]);
      gload_lds16(Vp + (size_t)row * SEQ + t * 64 + scol, &Vs[c * 512]);
    }
    __syncthreads();

    // S = Q K^T  (D: col=key=ln, row=q=g*4+r)
    f32x4 s[4];
    #pragma unroll
    for (int nt = 0; nt < 4; ++nt) {
      f32x4 z = {0.f, 0.f, 0.f, 0.f};
      s[nt] = z;
      #pragma unroll
      for (int kk = 0; kk < 2; ++kk) {
        int row = nt * 16 + ln;
        bf16x8 kF = *(const bf16x8*)&Ks[row * 64 + ((((kk << 2) | g) ^ (row & 7)) << 3)];
        s[nt] = mfma16(qF[kk], kF, s[nt]);
      }
    }
    // online softmax (log2 domain)
    #pragma unroll
    for (int r = 0; r < 4; ++r) {
      float rmax = fmaxf(fmaxf(s[0][r], s[1][r]), fmaxf(s[2][r], s[3][r])) * SC;
      #pragma unroll
      for (int off = 1; off <= 8; off <<= 1)
        rmax = fmaxf(rmax, __shfl_xor(rmax, off, 64));
      float nm = fmaxf(mrun[r], rmax);
      float al = exp2f(mrun[r] - nm);
      mrun[r] = nm;
      lrun[r] *= al;
      #pragma unroll
      for (int dt = 0; dt < 4; ++dt) o[dt][r] *= al;
      float ps = 0.f;
      #pragma unroll
      for (int nt = 0; nt < 4; ++nt) {
        float p = exp2f(s[nt][r] * SC - nm);
        ps += p;
        Ps[wid][(g * 4 + r) * 72 + nt * 16 + ln] = (bf16)p;
      }
      lrun[r] += ps;
    }
    // O += P V   (A = P from LDS, B = V via Vt rows)
    #pragma unroll
    for (int kk = 0; kk < 2; ++kk) {
      bf16x8 pF = *(const bf16x8*)&Ps[wid][ln * 72 + kk * 32 + g * 8];
      #pragma unroll
      for (int dt = 0; dt < 4; ++dt) {
        int row = dt * 16 + ln;
        bf16x8 vF = *(const bf16x8*)&Vs[row * 64 + ((((kk << 2) | g) ^ (row & 7)) << 3)];
        o[dt] = mfma16(pF, vF, o[dt]);
      }
    }
  }
  // finalize: reduce l across the 16-lane group, normalize, store [B*N, C]
  #pragma unroll
  for (int r = 0; r < 4; ++r) {
    #pragma unroll
    for (int off = 1; off <= 8; off <<= 1)
      lrun[r] += __shfl_xor(lrun[r], off, 64);
    lrun[r] = 1.0f / lrun[r];
  }
  const int b = bh / NHEAD, h = bh % NHEAD;
  #pragma unroll
  for (int dt = 0; dt < 4; ++dt)
    #pragma unroll
    for (int r = 0; r < 4; ++r) {
      size_t row = (size_t)b * SEQ + qt * 64 + wid * 16 + g * 4 + r;
      int col = h * 64 + dt * 16 + ln;
      Oa[row * CDIM + col] = (bf16)(o[dt][r] * lrun[r]);
    }
}

// ---------------- launch --------------------------------------------------
extern "C" void kernel_launch(void* const* d_in, const int* in_sizes, int n_in,
                              void* d_out, int out_size, void* d_ws, size_t ws_size,
                              hipStream_t stream) {
  const float* x      = (const float*)d_in[0];
  const float* w_qkv  = (const float*)d_in[1];
  const float* w_proj = (const float*)d_in[2];
  const float* b_proj = (const float*)d_in[3];

  char* ws = (char*)d_ws;
  // layout (bytes, all 256-aligned); total ~181 MB
  bf16* x_bf    = (bf16*)(ws + 0);                    // 25165824
  bf16* wqkv_bf = (bf16*)(ws + 25165824);             // 3538944
  bf16* wproj_bf= (bf16*)(ws + 28704768);             // 1179648
  bf16* qkv     = (bf16*)(ws + 29884416);             // 75497472
  bf16* attn_o  = qkv;                                // reuse (qkv dead after split)
  bf16* Qb      = (bf16*)(ws + 105381888);            // 25165824
  bf16* Kb      = (bf16*)(ws + 130547712);            // 25165824
  bf16* Vtb     = (bf16*)(ws + 155713536);            // 25165824

  cvt_bf16<<<dim3((MROWS*CDIM/8 + 255)/256), 256, 0, stream>>>(x, x_bf, MROWS*CDIM/8);
  cvt_bf16<<<dim3((NQKV*CDIM/8 + 255)/256), 256, 0, stream>>>(w_qkv, wqkv_bf, NQKV*CDIM/8);
  cvt_bf16<<<dim3((CDIM*CDIM/8 + 255)/256), 256, 0, stream>>>(w_proj, wproj_bf, CDIM*CDIM/8);

  gemm_bt<0><<<dim3((MROWS/128)*(NQKV/128)), 256, 0, stream>>>(
      x_bf, wqkv_bf, qkv, nullptr, MROWS, NQKV, CDIM);

  split_qkv<<<dim3(SEQ/64, NBATCH*NHEAD), 256, 0, stream>>>(qkv, Qb, Kb, Vtb);

  attn_fwd<<<dim3(SEQ/64, NBATCH*NHEAD), 256, 0, stream>>>(Qb, Kb, Vtb, attn_o);

  gemm_bt<1><<<dim3((MROWS/128)*(CDIM/128)), 256, 0, stream>>>(
      attn_o, wproj_bf, (float*)d_out, b_proj, MROWS, CDIM, CDIM);
}

// Round 3
// 372.138 us; speedup vs baseline: 1.1189x; 1.1189x over previous
//
#include <hip/hip_runtime.h>

typedef __bf16 bf16;
typedef __attribute__((ext_vector_type(8))) __bf16 bf16x8;
typedef __attribute__((ext_vector_type(4))) __bf16 bf16x4;
typedef __attribute__((ext_vector_type(4))) float f32x4;

#define NBATCH 8
#define NHEAD  12
#define SEQ    2048
#define DH     64
#define CDIM   768
#define MROWS  (NBATCH*SEQ)   /* 16384 */
#define NQKV   (3*CDIM)       /* 2304  */

__device__ __forceinline__ f32x4 mfma16(bf16x8 a, bf16x8 b, f32x4 c) {
  return __builtin_amdgcn_mfma_f32_16x16x32_bf16(a, b, c, 0, 0, 0);
}

__device__ __forceinline__ void gload_lds16(const void* g, void* l) {
  __builtin_amdgcn_global_load_lds((const __attribute__((address_space(1))) void*)g,
                                   (__attribute__((address_space(3))) void*)l,
                                   16, 0, 0);
}

// ---------------- fp32 -> bf16 convert ----------------
__global__ void cvt_bf16(const float* __restrict__ src, bf16* __restrict__ dst, int n8) {
  int i = blockIdx.x * 256 + threadIdx.x;
  if (i >= n8) return;
  const float4* s4 = (const float4*)src;
  float4 a = s4[2*i], c = s4[2*i+1];
  bf16x8 o;
  o[0]=(bf16)a.x; o[1]=(bf16)a.y; o[2]=(bf16)a.z; o[3]=(bf16)a.w;
  o[4]=(bf16)c.x; o[5]=(bf16)c.y; o[6]=(bf16)c.z; o[7]=(bf16)c.w;
  *(bf16x8*)(dst + (size_t)i*8) = o;
}

// ---------------- GEMM: C[M,N] = A[M,K] * B[N,K]^T (proven R1) -----------
template <int OUT_F32>
__global__ __launch_bounds__(256, 2)
void gemm_bt(const bf16* __restrict__ A, const bf16* __restrict__ Bm,
             void* __restrict__ Cout, const float* __restrict__ bias,
             int M, int Nn, int K) {
  __shared__ bf16 As[128*32];
  __shared__ bf16 Bs[128*32];
  const int tid = threadIdx.x, wid = tid >> 6, lane = tid & 63;
  const int g = lane >> 4, ln = lane & 15;
  const int ntn = Nn >> 7;
  const int gsz = 32 * ntn;
  const int grp = blockIdx.x / gsz;
  const int rem = blockIdx.x - grp * gsz;
  const int tm = grp * 32 + (rem & 31);
  const int tn = rem >> 5;
  const int m0 = tm << 7, n0 = tn << 7;
  const int wr = wid >> 1, wc = wid & 1;

  const int srow = lane >> 2;
  const int sslot = lane & 3;

  f32x4 acc[4][4] = {};

  const int nkt = K >> 5;
  for (int kt = 0; kt < nkt; ++kt) {
    if (kt) __syncthreads();
    #pragma unroll
    for (int i = 0; i < 2; ++i) {
      int c = wid * 2 + i;
      int row = c * 16 + srow;
      int colA = kt * 32 + ((sslot ^ (row & 3)) << 3);
      gload_lds16(A + (size_t)(m0 + row) * K + colA, &As[c * 512]);
      gload_lds16(Bm + (size_t)(n0 + row) * K + colA, &Bs[c * 512]);
    }
    __syncthreads();

    bf16x8 aF[4], bF[4];
    #pragma unroll
    for (int m = 0; m < 4; ++m) {
      int row = wr * 64 + m * 16 + ln;
      aF[m] = *(const bf16x8*)&As[row * 32 + ((g ^ (row & 3)) << 3)];
    }
    #pragma unroll
    for (int n = 0; n < 4; ++n) {
      int row = wc * 64 + n * 16 + ln;
      bF[n] = *(const bf16x8*)&Bs[row * 32 + ((g ^ (row & 3)) << 3)];
    }
    #pragma unroll
    for (int m = 0; m < 4; ++m)
      #pragma unroll
      for (int n = 0; n < 4; ++n)
        acc[m][n] = mfma16(aF[m], bF[n], acc[m][n]);
  }

  #pragma unroll
  for (int m = 0; m < 4; ++m) {
    int rowb = m0 + wr * 64 + m * 16 + g * 4;
    #pragma unroll
    for (int n = 0; n < 4; ++n) {
      int col = n0 + wc * 64 + n * 16 + ln;
      float bv = OUT_F32 ? bias[col] : 0.f;
      #pragma unroll
      for (int r = 0; r < 4; ++r) {
        if (OUT_F32)
          ((float*)Cout)[(size_t)(rowb + r) * Nn + col] = acc[m][n][r] + bv;
        else
          ((bf16*)Cout)[(size_t)(rowb + r) * Nn + col] = (bf16)acc[m][n][r];
      }
    }
  }
}

// ---------------- split: V section of qkv -> Vt ([B*H, D, N]) ------------
__global__ __launch_bounds__(256)
void split_v(const bf16* __restrict__ qkv, bf16* __restrict__ Vt) {
  __shared__ bf16 vlds[64 * 72];
  const int nt = blockIdx.x, bh = blockIdx.y;
  const int b = bh / NHEAD, h = bh % NHEAD;
  const int tid = threadIdx.x;
  const int nl = tid >> 2, quad = tid & 3;

  const bf16* s = qkv + ((size_t)(b * SEQ + nt * 64 + nl)) * NQKV + 2 * CDIM + h * DH + quad * 16;
  *(bf16x8*)&vlds[nl * 72 + quad * 16] = *(const bf16x8*)s;
  *(bf16x8*)&vlds[nl * 72 + quad * 16 + 8] = *(const bf16x8*)(s + 8);
  __syncthreads();
  const int dl = tid >> 2;
  bf16x8 w0, w1;
  #pragma unroll
  for (int j = 0; j < 8; ++j) {
    w0[j] = vlds[(quad * 16 + j) * 72 + dl];
    w1[j] = vlds[(quad * 16 + 8 + j) * 72 + dl];
  }
  bf16* d = Vt + ((size_t)bh * DH + dl) * SEQ + nt * 64 + quad * 16;
  *(bf16x8*)d = w0;
  *(bf16x8*)(d + 8) = w1;
}

// ---------------- flash attention fwd, swapped-QK^T + LDS-relayout PV ----
// QK^T swapped: s = mfma(K_frag, Q_frag) -> lane holds S[key=16nt+4g+r][q=ln];
// softmax in-lane + 2 shfl, m/l per-lane. P (all 16 values share q=ln) is
// written as 4x 8B stores into per-wave Ps[ln][key], read back as K=32
// A-fragments; V B-fragments come from swizzled Vs rows (same constants as
// the K reads). O in normal orientation (lane: q=g*4+r, d=dt*16+ln); the
// per-q rescale crosses layouts via 4 shfl.
__global__ __launch_bounds__(256, 3)
void attn_fwd3(const bf16* __restrict__ qkv, const bf16* __restrict__ Vt,
               bf16* __restrict__ Oa) {
  __shared__ bf16 Ks[2][64 * 64];
  __shared__ bf16 Vs[2][64 * 64];
  __shared__ bf16 Ps[4][16 * 72];
  const int tid = threadIdx.x, wid = tid >> 6, lane = tid & 63;
  const int g = lane >> 4, ln = lane & 15;
  const int qt = blockIdx.x, bh = blockIdx.y;
  const int b = bh / NHEAD, h = bh % NHEAD;

  // Q fragment (B role for QK^T): lane ln -> q-row, d-slice g*8 per kk
  const bf16* Qrow = qkv + ((size_t)b * SEQ + qt * 64 + wid * 16 + ln) * NQKV + h * DH;
  const bf16x8 qF0 = *(const bf16x8*)(Qrow + g * 8);
  const bf16x8 qF1 = *(const bf16x8*)(Qrow + 32 + g * 8);

  // staging (2 chunks/wave for each of K and V), pre-swizzled global source
  const int c0 = wid * 2, c1 = wid * 2 + 1;
  const int sr = lane >> 3;
  const int srow0 = c0 * 8 + sr, srow1 = c1 * 8 + sr;
  const int sw0 = ((lane & 7) ^ (srow0 & 7)) << 3;
  const int sw1 = ((lane & 7) ^ (srow1 & 7)) << 3;
  const bf16* k0 = qkv + ((size_t)b * SEQ + srow0) * NQKV + CDIM + h * DH + sw0;
  const bf16* k1 = qkv + ((size_t)b * SEQ + srow1) * NQKV + CDIM + h * DH + sw1;
  const bf16* v0 = Vt + ((size_t)bh * DH + srow0) * SEQ + sw0;
  const bf16* v1 = Vt + ((size_t)bh * DH + srow1) * SEQ + sw1;
  const size_t KADV = (size_t)64 * NQKV;

  // loop-invariant LDS read offsets (elements); shared by K and V reads
  const int e = ln & 7;
  const int off0 = ln * 64 + ((g ^ e) << 3);          // 16B slot g   of row (blk*16+ln)
  const int off1 = ln * 64 + (((4 | g) ^ e) << 3);    // 16B slot 4|g
  bf16* PsW = &Ps[wid][0];
  const int psw = ln * 72 + g * 4;                    // write base (key = nt*16 + g*4)
  const int psr = ln * 72 + g * 8;                    // read base  (key = kk*32 + g*8)

  f32x4 o[4] = {};
  float mrun = -3.0e38f, lrun = 0.f;
  const float SC = 0.125f * 1.44269504088896f;  // D^-0.5 * log2(e)

  gload_lds16(k0, &Ks[0][c0 * 512]);
  gload_lds16(k1, &Ks[0][c1 * 512]);
  gload_lds16(v0, &Vs[0][c0 * 512]);
  gload_lds16(v1, &Vs[0][c1 * 512]);
  __syncthreads();

  int cur = 0;
  for (int t = 0; t < SEQ / 64; ++t) {
    if (t < SEQ / 64 - 1) {   // stage next tile (drained by end-of-iter barrier)
      k0 += KADV; k1 += KADV; v0 += 64; v1 += 64;
      const int nb = cur ^ 1;
      gload_lds16(k0, &Ks[nb][c0 * 512]);
      gload_lds16(k1, &Ks[nb][c1 * 512]);
      gload_lds16(v0, &Vs[nb][c0 * 512]);
      gload_lds16(v1, &Vs[nb][c1 * 512]);
    }
    const bf16* KsB = &Ks[cur][0];
    const bf16* VsB = &Vs[cur][0];

    // S^T = mfma(K, Q): s[nt][r] = S[key=nt*16+g*4+r][q=ln]
    f32x4 s[4] = {};
    #pragma unroll
    for (int nt = 0; nt < 4; ++nt)
      s[nt] = mfma16(*(const bf16x8*)(KsB + off0 + nt * 1024), qF0, s[nt]);
    #pragma unroll
    for (int nt = 0; nt < 4; ++nt)
      s[nt] = mfma16(*(const bf16x8*)(KsB + off1 + nt * 1024), qF1, s[nt]);

    // in-lane max over 16 keys + cross-g reduce (2 shfl)
    float m0 = fmaxf(fmaxf(s[0][0], s[0][1]), fmaxf(s[0][2], s[0][3]));
    float m1 = fmaxf(fmaxf(s[1][0], s[1][1]), fmaxf(s[1][2], s[1][3]));
    float m2 = fmaxf(fmaxf(s[2][0], s[2][1]), fmaxf(s[2][2], s[2][3]));
    float m3 = fmaxf(fmaxf(s[3][0], s[3][1]), fmaxf(s[3][2], s[3][3]));
    float rmax = fmaxf(fmaxf(m0, m1), fmaxf(m2, m3));
    rmax = fmaxf(rmax, __shfl_xor(rmax, 16, 64));
    rmax = fmaxf(rmax, __shfl_xor(rmax, 32, 64));

    float nm = fmaxf(mrun, rmax * SC);
    float al = exp2f(mrun - nm);
    mrun = nm;
    lrun *= al;

    // rescale O (output rows are q = g*4+r -> fetch al via shfl)
    float alr[4];
    #pragma unroll
    for (int r = 0; r < 4; ++r) alr[r] = __shfl(al, g * 4 + r, 64);
    #pragma unroll
    for (int dt = 0; dt < 4; ++dt)
      #pragma unroll
      for (int r = 0; r < 4; ++r) o[dt][r] *= alr[r];

    // P = exp2(S*SC - nm), accumulate l, write to per-wave Ps[q=ln][key]
    #pragma unroll
    for (int nt = 0; nt < 4; ++nt) {
      bf16x4 pk;
      #pragma unroll
      for (int r = 0; r < 4; ++r) {
        float p = exp2f(s[nt][r] * SC - nm);
        lrun += p;
        pk[r] = (bf16)p;
      }
      *(bf16x4*)(PsW + psw + nt * 16) = pk;
    }

    // O += P V : A-frag P from Ps rows, B-frag V from Vs rows (K=32 builtin)
    #pragma unroll
    for (int kk = 0; kk < 2; ++kk) {
      bf16x8 pF = *(const bf16x8*)(PsW + psr + kk * 32);
      const int voff = kk ? off1 : off0;
      #pragma unroll
      for (int dt = 0; dt < 4; ++dt) {
        bf16x8 vF = *(const bf16x8*)(VsB + voff + dt * 1024);
        o[dt] = mfma16(pF, vF, o[dt]);
      }
    }
    __syncthreads();   // drains vmcnt -> next buffer ready; Ps reuse safe
    cur ^= 1;
  }

  // finalize: l total per q (lane-local q=ln), cross to output layout via shfl
  float ltot = lrun + __shfl_xor(lrun, 16, 64);
  ltot += __shfl_xor(ltot, 32, 64);
  const float inv = 1.0f / ltot;
  float invr[4];
  #pragma unroll
  for (int r = 0; r < 4; ++r) invr[r] = __shfl(inv, g * 4 + r, 64);

  // store: lane holds O[q = g*4+r][d = dt*16+ln]
  #pragma unroll
  for (int r = 0; r < 4; ++r) {
    bf16* Orow = Oa + ((size_t)b * SEQ + qt * 64 + wid * 16 + g * 4 + r) * CDIM + h * DH + ln;
    #pragma unroll
    for (int dt = 0; dt < 4; ++dt)
      Orow[dt * 16] = (bf16)(o[dt][r] * invr[r]);
  }
}

// ---------------- launch --------------------------------------------------
extern "C" void kernel_launch(void* const* d_in, const int* in_sizes, int n_in,
                              void* d_out, int out_size, void* d_ws, size_t ws_size,
                              hipStream_t stream) {
  const float* x      = (const float*)d_in[0];
  const float* w_qkv  = (const float*)d_in[1];
  const float* w_proj = (const float*)d_in[2];
  const float* b_proj = (const float*)d_in[3];

  char* ws = (char*)d_ws;
  bf16* x_bf    = (bf16*)(ws + 0);                    // 25165824
  bf16* wqkv_bf = (bf16*)(ws + 25165824);             // 3538944
  bf16* wproj_bf= (bf16*)(ws + 28704768);             // 1179648
  bf16* qkv     = (bf16*)(ws + 29884416);             // 75497472
  bf16* attn_o  = (bf16*)(ws + 105381888);            // 25165824
  bf16* Vtb     = (bf16*)(ws + 130547712);            // 25165824

  cvt_bf16<<<dim3((MROWS*CDIM/8 + 255)/256), 256, 0, stream>>>(x, x_bf, MROWS*CDIM/8);
  cvt_bf16<<<dim3((NQKV*CDIM/8 + 255)/256), 256, 0, stream>>>(w_qkv, wqkv_bf, NQKV*CDIM/8);
  cvt_bf16<<<dim3((CDIM*CDIM/8 + 255)/256), 256, 0, stream>>>(w_proj, wproj_bf, CDIM*CDIM/8);

  gemm_bt<0><<<dim3((MROWS/128)*(NQKV/128)), 256, 0, stream>>>(
      x_bf, wqkv_bf, qkv, nullptr, MROWS, NQKV, CDIM);

  split_v<<<dim3(SEQ/64, NBATCH*NHEAD), 256, 0, stream>>>(qkv, Vtb);

  attn_fwd3<<<dim3(SEQ/64, NBATCH*NHEAD), 256, 0, stream>>>(qkv, Vtb, attn_o);

  gemm_bt<1><<<dim3((MROWS/128)*(CDIM/128)), 256, 0, stream>>>(
      attn_o, wproj_bf, (float*)d_out, b_proj, MROWS, CDIM, CDIM);
}

// Round 4
// 328.938 us; speedup vs baseline: 1.2658x; 1.1313x over previous
//
#include <hip/hip_runtime.h>

typedef __bf16 bf16;
typedef __attribute__((ext_vector_type(8))) __bf16 bf16x8;
typedef __attribute__((ext_vector_type(4))) __bf16 bf16x4;
typedef __attribute__((ext_vector_type(4))) float f32x4;

#define NBATCH 8
#define NHEAD  12
#define SEQ    2048
#define DH     64
#define CDIM   768
#define MROWS  (NBATCH*SEQ)   /* 16384 */
#define NQKV   (3*CDIM)       /* 2304  */

__device__ __forceinline__ f32x4 mfma16(bf16x8 a, bf16x8 b, f32x4 c) {
  return __builtin_amdgcn_mfma_f32_16x16x32_bf16(a, b, c, 0, 0, 0);
}

__device__ __forceinline__ void gload_lds16(const void* g, void* l) {
  __builtin_amdgcn_global_load_lds((const __attribute__((address_space(1))) void*)g,
                                   (__attribute__((address_space(3))) void*)l,
                                   16, 0, 0);
}

// pack 2 f32 -> 1 u32 of 2 bf16 (T12; no builtin on gfx950, guide m240)
__device__ __forceinline__ unsigned cvt_pk_bf16(float lo, float hi) {
  unsigned r;
  asm("v_cvt_pk_bf16_f32 %0, %1, %2" : "=v"(r) : "v"(lo), "v"(hi));
  return r;
}

// ---------------- fp32 -> bf16 convert ----------------
__global__ void cvt_bf16(const float* __restrict__ src, bf16* __restrict__ dst, int n8) {
  int i = blockIdx.x * 256 + threadIdx.x;
  if (i >= n8) return;
  const float4* s4 = (const float4*)src;
  float4 a = s4[2*i], c = s4[2*i+1];
  bf16x8 o;
  o[0]=(bf16)a.x; o[1]=(bf16)a.y; o[2]=(bf16)a.z; o[3]=(bf16)a.w;
  o[4]=(bf16)c.x; o[5]=(bf16)c.y; o[6]=(bf16)c.z; o[7]=(bf16)c.w;
  *(bf16x8*)(dst + (size_t)i*8) = o;
}

// ---------------- GEMM: C[M,N] = A[M,K] * B[N,K]^T (proven R1) -----------
template <int OUT_F32>
__global__ __launch_bounds__(256, 2)
void gemm_bt(const bf16* __restrict__ A, const bf16* __restrict__ Bm,
             void* __restrict__ Cout, const float* __restrict__ bias,
             int M, int Nn, int K) {
  __shared__ bf16 As[128*32];
  __shared__ bf16 Bs[128*32];
  const int tid = threadIdx.x, wid = tid >> 6, lane = tid & 63;
  const int g = lane >> 4, ln = lane & 15;
  const int ntn = Nn >> 7;
  const int gsz = 32 * ntn;
  const int grp = blockIdx.x / gsz;
  const int rem = blockIdx.x - grp * gsz;
  const int tm = grp * 32 + (rem & 31);
  const int tn = rem >> 5;
  const int m0 = tm << 7, n0 = tn << 7;
  const int wr = wid >> 1, wc = wid & 1;

  const int srow = lane >> 2;
  const int sslot = lane & 3;

  f32x4 acc[4][4] = {};

  const int nkt = K >> 5;
  for (int kt = 0; kt < nkt; ++kt) {
    if (kt) __syncthreads();
    #pragma unroll
    for (int i = 0; i < 2; ++i) {
      int c = wid * 2 + i;
      int row = c * 16 + srow;
      int colA = kt * 32 + ((sslot ^ (row & 3)) << 3);
      gload_lds16(A + (size_t)(m0 + row) * K + colA, &As[c * 512]);
      gload_lds16(Bm + (size_t)(n0 + row) * K + colA, &Bs[c * 512]);
    }
    __syncthreads();

    bf16x8 aF[4], bF[4];
    #pragma unroll
    for (int m = 0; m < 4; ++m) {
      int row = wr * 64 + m * 16 + ln;
      aF[m] = *(const bf16x8*)&As[row * 32 + ((g ^ (row & 3)) << 3)];
    }
    #pragma unroll
    for (int n = 0; n < 4; ++n) {
      int row = wc * 64 + n * 16 + ln;
      bF[n] = *(const bf16x8*)&Bs[row * 32 + ((g ^ (row & 3)) << 3)];
    }
    #pragma unroll
    for (int m = 0; m < 4; ++m)
      #pragma unroll
      for (int n = 0; n < 4; ++n)
        acc[m][n] = mfma16(aF[m], bF[n], acc[m][n]);
  }

  #pragma unroll
  for (int m = 0; m < 4; ++m) {
    int rowb = m0 + wr * 64 + m * 16 + g * 4;
    #pragma unroll
    for (int n = 0; n < 4; ++n) {
      int col = n0 + wc * 64 + n * 16 + ln;
      float bv = OUT_F32 ? bias[col] : 0.f;
      #pragma unroll
      for (int r = 0; r < 4; ++r) {
        if (OUT_F32)
          ((float*)Cout)[(size_t)(rowb + r) * Nn + col] = acc[m][n][r] + bv;
        else
          ((bf16*)Cout)[(size_t)(rowb + r) * Nn + col] = (bf16)acc[m][n][r];
      }
    }
  }
}

// ---------------- split: V section of qkv -> Vt ([B*H, D, N]) ------------
__global__ __launch_bounds__(256)
void split_v(const bf16* __restrict__ qkv, bf16* __restrict__ Vt) {
  __shared__ bf16 vlds[64 * 72];
  const int nt = blockIdx.x, bh = blockIdx.y;
  const int b = bh / NHEAD, h = bh % NHEAD;
  const int tid = threadIdx.x;
  const int nl = tid >> 2, quad = tid & 3;

  const bf16* s = qkv + ((size_t)(b * SEQ + nt * 64 + nl)) * NQKV + 2 * CDIM + h * DH + quad * 16;
  *(bf16x8*)&vlds[nl * 72 + quad * 16] = *(const bf16x8*)s;
  *(bf16x8*)&vlds[nl * 72 + quad * 16 + 8] = *(const bf16x8*)(s + 8);
  __syncthreads();
  const int dl = tid >> 2;
  bf16x8 w0, w1;
  #pragma unroll
  for (int j = 0; j < 8; ++j) {
    w0[j] = vlds[(quad * 16 + j) * 72 + dl];
    w1[j] = vlds[(quad * 16 + 8 + j) * 72 + dl];
  }
  bf16* d = Vt + ((size_t)bh * DH + dl) * SEQ + nt * 64 + quad * 16;
  *(bf16x8*)d = w0;
  *(bf16x8*)(d + 8) = w1;
}

// ---------------- flash attention fwd ------------------------------------
// Swapped QK^T (lane: q=ln across 16 key-regs), defer-max online softmax
// (THR=8), P->bf16 via v_cvt_pk_bf16_f32, l accumulated by an extra
// MFMA P*ones (lands directly in output layout q=g*4+r), Ps relayout in
// 128B-row XOR-swizzled LDS (reads share off0/off1 with K/V; conflict-free).
__global__ __launch_bounds__(256, 4)
void attn_fwd4(const bf16* __restrict__ qkv, const bf16* __restrict__ Vt,
               bf16* __restrict__ Oa) {
  __shared__ bf16 Ks[2][64 * 64];
  __shared__ bf16 Vs[2][64 * 64];
  __shared__ bf16 Ps[4][16 * 64];
  const int tid = threadIdx.x, wid = tid >> 6, lane = tid & 63;
  const int g = lane >> 4, ln = lane & 15;
  const int qt = blockIdx.x, bh = blockIdx.y;
  const int b = bh / NHEAD, h = bh % NHEAD;

  // Q fragment (B role for QK^T): lane ln -> q-row, d-slice g*8 per kk
  const bf16* Qrow = qkv + ((size_t)b * SEQ + qt * 64 + wid * 16 + ln) * NQKV + h * DH;
  const bf16x8 qF0 = *(const bf16x8*)(Qrow + g * 8);
  const bf16x8 qF1 = *(const bf16x8*)(Qrow + 32 + g * 8);

  // staging (2 chunks/wave for each of K and V), pre-swizzled global source
  const int c0 = wid * 2, c1 = wid * 2 + 1;
  const int sr = lane >> 3;
  const int srow0 = c0 * 8 + sr, srow1 = c1 * 8 + sr;
  const int sw0 = ((lane & 7) ^ (srow0 & 7)) << 3;
  const int sw1 = ((lane & 7) ^ (srow1 & 7)) << 3;
  const bf16* k0 = qkv + ((size_t)b * SEQ + srow0) * NQKV + CDIM + h * DH + sw0;
  const bf16* k1 = qkv + ((size_t)b * SEQ + srow1) * NQKV + CDIM + h * DH + sw1;
  const bf16* v0 = Vt + ((size_t)bh * DH + srow0) * SEQ + sw0;
  const bf16* v1 = Vt + ((size_t)bh * DH + srow1) * SEQ + sw1;
  const size_t KADV = (size_t)64 * NQKV;

  // loop-invariant LDS offsets (elements); shared by K/V/Ps-read
  const int e7 = ln & 7;
  const int off0 = ln * 64 + ((g ^ e7) << 3);
  const int off1 = ln * 64 + (((4 | g) ^ e7) << 3);
  bf16* PsW = &Ps[wid][0];
  int pswo[4];
  #pragma unroll
  for (int nt = 0; nt < 4; ++nt)
    pswo[nt] = ln * 64 + ((((nt * 2) + (g >> 1)) ^ e7) << 3) + ((g & 1) << 2);

  const bf16 one = (bf16)1.0f;
  const bf16x8 onesF = {one, one, one, one, one, one, one, one};

  f32x4 o[4] = {};
  f32x4 lacc = {0.f, 0.f, 0.f, 0.f};
  float m_reg = -3.0e38f;
  const float SC = 0.125f * 1.44269504088896f;  // D^-0.5 * log2(e)

  gload_lds16(k0, &Ks[0][c0 * 512]);
  gload_lds16(k1, &Ks[0][c1 * 512]);
  gload_lds16(v0, &Vs[0][c0 * 512]);
  gload_lds16(v1, &Vs[0][c1 * 512]);
  __syncthreads();

  int cur = 0;
  for (int t = 0; t < SEQ / 64; ++t) {
    if (t < SEQ / 64 - 1) {   // stage next tile (drained by end-of-iter barrier)
      k0 += KADV; k1 += KADV; v0 += 64; v1 += 64;
      const int nb = cur ^ 1;
      gload_lds16(k0, &Ks[nb][c0 * 512]);
      gload_lds16(k1, &Ks[nb][c1 * 512]);
      gload_lds16(v0, &Vs[nb][c0 * 512]);
      gload_lds16(v1, &Vs[nb][c1 * 512]);
    }
    const bf16* KsB = &Ks[cur][0];
    const bf16* VsB = &Vs[cur][0];

    // S^T = mfma(K, Q): s[nt][r] = S[key=nt*16+g*4+r][q=ln]
    f32x4 s[4] = {};
    #pragma unroll
    for (int nt = 0; nt < 4; ++nt)
      s[nt] = mfma16(*(const bf16x8*)(KsB + off0 + nt * 1024), qF0, s[nt]);
    #pragma unroll
    for (int nt = 0; nt < 4; ++nt)
      s[nt] = mfma16(*(const bf16x8*)(KsB + off1 + nt * 1024), qF1, s[nt]);

    // per-q max: in-lane over 16 keys + cross-g (2 shfl)
    float m0 = fmaxf(fmaxf(s[0][0], s[0][1]), fmaxf(s[0][2], s[0][3]));
    float m1 = fmaxf(fmaxf(s[1][0], s[1][1]), fmaxf(s[1][2], s[1][3]));
    float m2 = fmaxf(fmaxf(s[2][0], s[2][1]), fmaxf(s[2][2], s[2][3]));
    float m3 = fmaxf(fmaxf(s[3][0], s[3][1]), fmaxf(s[3][2], s[3][3]));
    float rmax = fmaxf(fmaxf(m0, m1), fmaxf(m2, m3));
    rmax = fmaxf(rmax, __shfl_xor(rmax, 16, 64));
    rmax = fmaxf(rmax, __shfl_xor(rmax, 32, 64));
    const float rs = rmax * SC;

    // defer-max (T13): only rescale when some row's max grew past THR=8
    if (__any(rs > m_reg + 8.0f)) {
      float nm = fmaxf(m_reg, rs);
      float al = exp2f(m_reg - nm);
      m_reg = nm;
      float alr[4];
      #pragma unroll
      for (int r = 0; r < 4; ++r) alr[r] = __shfl(al, g * 4 + r, 64);
      #pragma unroll
      for (int dt = 0; dt < 4; ++dt)
        #pragma unroll
        for (int r = 0; r < 4; ++r) o[dt][r] *= alr[r];
      #pragma unroll
      for (int r = 0; r < 4; ++r) lacc[r] *= alr[r];
    }

    // P = exp2(S*SC - m_reg)  (bounded by 2^8), pack via cvt_pk, 8B stores
    #pragma unroll
    for (int nt = 0; nt < 4; ++nt) {
      float p0 = exp2f(s[nt][0] * SC - m_reg);
      float p1 = exp2f(s[nt][1] * SC - m_reg);
      float p2 = exp2f(s[nt][2] * SC - m_reg);
      float p3 = exp2f(s[nt][3] * SC - m_reg);
      uint2 w;
      w.x = cvt_pk_bf16(p0, p1);
      w.y = cvt_pk_bf16(p2, p3);
      *(uint2*)(PsW + pswo[nt]) = w;
    }

    // O += P V ; l += P * ones (lands in output layout q=g*4+r)
    #pragma unroll
    for (int kk = 0; kk < 2; ++kk) {
      bf16x8 pF = *(const bf16x8*)(PsW + (kk ? off1 : off0));
      lacc = mfma16(pF, onesF, lacc);
      const int voff = kk ? off1 : off0;
      #pragma unroll
      for (int dt = 0; dt < 4; ++dt) {
        bf16x8 vF = *(const bf16x8*)(VsB + voff + dt * 1024);
        o[dt] = mfma16(pF, vF, o[dt]);
      }
    }
    __syncthreads();   // drains vmcnt -> next buffer ready; Ps reuse safe
    cur ^= 1;
  }

  // normalize: lacc[r] = l[q=g*4+r] already in output layout
  float invr[4];
  #pragma unroll
  for (int r = 0; r < 4; ++r) invr[r] = 1.0f / lacc[r];

  // store: lane holds O[q = g*4+r][d = dt*16+ln]
  #pragma unroll
  for (int r = 0; r < 4; ++r) {
    bf16* Orow = Oa + ((size_t)b * SEQ + qt * 64 + wid * 16 + g * 4 + r) * CDIM + h * DH + ln;
    #pragma unroll
    for (int dt = 0; dt < 4; ++dt)
      Orow[dt * 16] = (bf16)(o[dt][r] * invr[r]);
  }
}

// ---------------- launch --------------------------------------------------
extern "C" void kernel_launch(void* const* d_in, const int* in_sizes, int n_in,
                              void* d_out, int out_size, void* d_ws, size_t ws_size,
                              hipStream_t stream) {
  const float* x      = (const float*)d_in[0];
  const float* w_qkv  = (const float*)d_in[1];
  const float* w_proj = (const float*)d_in[2];
  const float* b_proj = (const float*)d_in[3];

  char* ws = (char*)d_ws;
  bf16* x_bf    = (bf16*)(ws + 0);                    // 25165824
  bf16* wqkv_bf = (bf16*)(ws + 25165824);             // 3538944
  bf16* wproj_bf= (bf16*)(ws + 28704768);             // 1179648
  bf16* qkv     = (bf16*)(ws + 29884416);             // 75497472
  bf16* attn_o  = (bf16*)(ws + 105381888);            // 25165824
  bf16* Vtb     = (bf16*)(ws + 130547712);            // 25165824

  cvt_bf16<<<dim3((MROWS*CDIM/8 + 255)/256), 256, 0, stream>>>(x, x_bf, MROWS*CDIM/8);
  cvt_bf16<<<dim3((NQKV*CDIM/8 + 255)/256), 256, 0, stream>>>(w_qkv, wqkv_bf, NQKV*CDIM/8);
  cvt_bf16<<<dim3((CDIM*CDIM/8 + 255)/256), 256, 0, stream>>>(w_proj, wproj_bf, CDIM*CDIM/8);

  gemm_bt<0><<<dim3((MROWS/128)*(NQKV/128)), 256, 0, stream>>>(
      x_bf, wqkv_bf, qkv, nullptr, MROWS, NQKV, CDIM);

  split_v<<<dim3(SEQ/64, NBATCH*NHEAD), 256, 0, stream>>>(qkv, Vtb);

  attn_fwd4<<<dim3(SEQ/64, NBATCH*NHEAD), 256, 0, stream>>>(qkv, Vtb, attn_o);

  gemm_bt<1><<<dim3((MROWS/128)*(CDIM/128)), 256, 0, stream>>>(
      attn_o, wproj_bf, (float*)d_out, b_proj, MROWS, CDIM, CDIM);
}